// Round 1
// baseline (186.542 us; speedup 1.0000x reference)
//
#include <hip/hip_runtime.h>

// LBS skinning: out[b,v,i] = sum_j w[v,j] * (M[b,j,i,:3] . vert[v] + M[b,j,i,3])
// vertices:  [1,V,3]  fp32   (d_in[0])
// weights:   [1,V,J]  fp32   (d_in[1]),  J = 52
// xforms:    [B,J,4,4] fp32  (d_in[2]),  B = 32
// out:       [B,V,3]  fp32

constexpr int JN  = 52;  // joints
constexpr int BPT = 8;   // batches per thread (grid.y covers B/BPT groups)

__global__ __launch_bounds__(256) void skin_fp32(
    const float* __restrict__ verts,
    const float* __restrict__ weights,
    const float* __restrict__ xf,
    float* __restrict__ out,
    int V)
{
    const int v  = blockIdx.x * 256 + threadIdx.x;
    const int b0 = blockIdx.y * BPT;
    if (v >= V) return;

    const float vx = verts[3 * (size_t)v + 0];
    const float vy = verts[3 * (size_t)v + 1];
    const float vz = verts[3 * (size_t)v + 2];

    float acc[BPT][3];
#pragma unroll
    for (int bi = 0; bi < BPT; ++bi) {
        acc[bi][0] = 0.f; acc[bi][1] = 0.f; acc[bi][2] = 0.f;
    }

    // weight row: 52 floats = 208 B, 16B-aligned (208 = 13*16)
    const float4* __restrict__ wrow =
        reinterpret_cast<const float4*>(weights + (size_t)v * JN);

    for (int jc = 0; jc < JN / 4; ++jc) {
        const float4 w4 = wrow[jc];
        float w[4] = { w4.x, w4.y, w4.z, w4.w };
        float wx[4], wy[4], wz[4];
#pragma unroll
        for (int jj = 0; jj < 4; ++jj) {
            wx[jj] = w[jj] * vx;
            wy[jj] = w[jj] * vy;
            wz[jj] = w[jj] * vz;
        }

#pragma unroll
        for (int bi = 0; bi < BPT; ++bi) {
            // wave-uniform address (no dependence on v) -> scalar loads
            const float* __restrict__ m =
                xf + ((size_t)(b0 + bi) * JN + (size_t)jc * 4) * 16;
#pragma unroll
            for (int jj = 0; jj < 4; ++jj) {
                const float* mj = m + jj * 16;
                acc[bi][0] = fmaf(wx[jj], mj[0],
                             fmaf(wy[jj], mj[1],
                             fmaf(wz[jj], mj[2],
                             fmaf(w[jj],  mj[3], acc[bi][0]))));
                acc[bi][1] = fmaf(wx[jj], mj[4],
                             fmaf(wy[jj], mj[5],
                             fmaf(wz[jj], mj[6],
                             fmaf(w[jj],  mj[7], acc[bi][1]))));
                acc[bi][2] = fmaf(wx[jj], mj[8],
                             fmaf(wy[jj], mj[9],
                             fmaf(wz[jj], mj[10],
                             fmaf(w[jj],  mj[11], acc[bi][2]))));
            }
        }
    }

#pragma unroll
    for (int bi = 0; bi < BPT; ++bi) {
        const size_t o = ((size_t)(b0 + bi) * (size_t)V + (size_t)v) * 3;
        out[o + 0] = acc[bi][0];
        out[o + 1] = acc[bi][1];
        out[o + 2] = acc[bi][2];
    }
}

extern "C" void kernel_launch(void* const* d_in, const int* in_sizes, int n_in,
                              void* d_out, int out_size, void* d_ws, size_t ws_size,
                              hipStream_t stream)
{
    const float* verts   = (const float*)d_in[0];
    const float* weights = (const float*)d_in[1];
    const float* xf      = (const float*)d_in[2];
    float* out = (float*)d_out;

    const int V = in_sizes[0] / 3;            // 100000
    const int B = in_sizes[2] / (JN * 16);    // 32

    dim3 grid((V + 255) / 256, B / BPT);
    skin_fp32<<<grid, 256, 0, stream>>>(verts, weights, xf, out, V);
}

// Round 2
// 44.624 us; speedup vs baseline: 4.1803x; 4.1803x over previous
//
#include <hip/hip_runtime.h>

// LBS skinning as bf16 MFMA GEMM:
//   out[v, n=3b+i] = sum_{k=4j+c} X[v,k] * A[k,n]
//   X[v,4j+c] = w[v,j] * h_v[c],  h_v = (x,y,z,1)
//   A[4j+c,3b+i] = M[b,j,i,c]
// M=V=100000, N=96, K=208 (padded to 224 = 7 steps of 32)

typedef __attribute__((ext_vector_type(8))) short bf16x8;
typedef __attribute__((ext_vector_type(4))) float f32x4;

constexpr int J      = 52;
constexpr int KSTEPS = 7;    // 7 x K=32 (224, zero-padded past 208)
constexpr int NT     = 6;    // 6 n-tiles of 16 -> N=96
constexpr int MT     = 2;    // m-tiles (of 16 vertices) per wave
constexpr int WAVES  = 4;
constexpr int VPB    = WAVES * MT * 16;  // 128 vertices per block

__device__ __forceinline__ unsigned short f2bf(float f) {
    union { float f; unsigned u; } cv; cv.f = f;
    unsigned u = cv.u;
    u += 0x7FFFu + ((u >> 16) & 1u);   // round-to-nearest-even
    return (unsigned short)(u >> 16);
}

__global__ __launch_bounds__(256) void skin_mfma(
    const float* __restrict__ verts,
    const float* __restrict__ weights,
    const float* __restrict__ xf,
    float* __restrict__ out,
    int V)
{
    // B-fragments of A, pre-packed in MFMA lane order: [kstep][ntile][lane]
    __shared__ bf16x8 Bp[KSTEPS * NT * 64];

    // ---- pre-pack A into LDS (whole block cooperates) ----
    const float4* __restrict__ xf4 = reinterpret_cast<const float4*>(xf);
    for (int slot = threadIdx.x; slot < KSTEPS * NT * 64; slot += 256) {
        const int s    = slot / (NT * 64);
        const int rem  = slot - s * (NT * 64);
        const int t    = rem >> 6;
        const int l    = rem & 63;
        const int lgrp = l >> 4;
        const int lrow = l & 15;
        const int n = t * 16 + lrow;          // n = 3b + i, always < 96
        const int b = n / 3;
        const int i = n - 3 * b;
        const int j0 = s * 8 + lgrp * 2;      // elems 0-3 -> joint j0, 4-7 -> j0+1
        float4 m0 = {0,0,0,0}, m1 = {0,0,0,0};
        if (j0 < J)     m0 = xf4[(b * J + j0) * 4 + i];
        if (j0 + 1 < J) m1 = xf4[(b * J + j0 + 1) * 4 + i];
        bf16x8 r;
        r[0] = (short)f2bf(m0.x); r[1] = (short)f2bf(m0.y);
        r[2] = (short)f2bf(m0.z); r[3] = (short)f2bf(m0.w);
        r[4] = (short)f2bf(m1.x); r[5] = (short)f2bf(m1.y);
        r[6] = (short)f2bf(m1.z); r[7] = (short)f2bf(m1.w);
        Bp[slot] = r;
    }
    __syncthreads();

    // ---- per-wave GEMM: 2 m-tiles x 6 n-tiles ----
    const int lane = threadIdx.x & 63;
    const int wid  = threadIdx.x >> 6;
    const int lgrp = lane >> 4;
    const int lrow = lane & 15;
    const int v0   = blockIdx.x * VPB + wid * (MT * 16);

    // one vertex per lane per m-tile (lanes 16-63 mirror 0-15's vertices)
    float hx[MT], hy[MT], hz[MT];
    int   vv[MT];
    bool  vok[MT];
#pragma unroll
    for (int mt = 0; mt < MT; ++mt) {
        const int v = v0 + mt * 16 + lrow;
        vv[mt]  = v;
        vok[mt] = (v < V);
        hx[mt] = vok[mt] ? verts[3 * (size_t)v + 0] : 0.f;
        hy[mt] = vok[mt] ? verts[3 * (size_t)v + 1] : 0.f;
        hz[mt] = vok[mt] ? verts[3 * (size_t)v + 2] : 0.f;
    }

    f32x4 acc[MT][NT];
#pragma unroll
    for (int mt = 0; mt < MT; ++mt)
#pragma unroll
        for (int t = 0; t < NT; ++t)
            acc[mt][t] = f32x4{0.f, 0.f, 0.f, 0.f};

    for (int s = 0; s < KSTEPS; ++s) {
        const int j0 = s * 8 + lgrp * 2;
        bf16x8 afrag[MT];
#pragma unroll
        for (int mt = 0; mt < MT; ++mt) {
            float w0 = 0.f, w1 = 0.f;
            if (vok[mt] && j0 < J) {
                const float2 wp = *reinterpret_cast<const float2*>(
                    weights + (size_t)vv[mt] * J + j0);
                w0 = wp.x; w1 = wp.y;
            }
            bf16x8 a;
            a[0] = (short)f2bf(w0 * hx[mt]); a[1] = (short)f2bf(w0 * hy[mt]);
            a[2] = (short)f2bf(w0 * hz[mt]); a[3] = (short)f2bf(w0);
            a[4] = (short)f2bf(w1 * hx[mt]); a[5] = (short)f2bf(w1 * hy[mt]);
            a[6] = (short)f2bf(w1 * hz[mt]); a[7] = (short)f2bf(w1);
            afrag[mt] = a;
        }
#pragma unroll
        for (int t = 0; t < NT; ++t) {
            const bf16x8 bfrag = Bp[(s * NT + t) * 64 + lane];
            acc[0][t] = __builtin_amdgcn_mfma_f32_16x16x32_bf16(
                afrag[0], bfrag, acc[0][t], 0, 0, 0);
            acc[1][t] = __builtin_amdgcn_mfma_f32_16x16x32_bf16(
                afrag[1], bfrag, acc[1][t], 0, 0, 0);
        }
    }

    // ---- store: lane holds D[v0m + lgrp*4 + r][t*16 + lrow], r=0..3 ----
#pragma unroll
    for (int mt = 0; mt < MT; ++mt) {
        const int vbase = v0 + mt * 16 + lgrp * 4;
#pragma unroll
        for (int t = 0; t < NT; ++t) {
            const int n = t * 16 + lrow;
            const int b = n / 3;
            const int i = n - 3 * b;
            const size_t base = (size_t)b * (size_t)V * 3 + i;
#pragma unroll
            for (int r = 0; r < 4; ++r) {
                const int v = vbase + r;
                if (v < V) out[base + (size_t)v * 3] = acc[mt][t][r];
            }
        }
    }
}

extern "C" void kernel_launch(void* const* d_in, const int* in_sizes, int n_in,
                              void* d_out, int out_size, void* d_ws, size_t ws_size,
                              hipStream_t stream)
{
    const float* verts   = (const float*)d_in[0];
    const float* weights = (const float*)d_in[1];
    const float* xf      = (const float*)d_in[2];
    float* out = (float*)d_out;

    const int V = in_sizes[0] / 3;   // 100000
    const int nblocks = (V + VPB - 1) / VPB;
    skin_mfma<<<nblocks, 256, 0, stream>>>(verts, weights, xf, out, V);
}